// Round 1
// baseline (126.706 us; speedup 1.0000x reference)
//
#include <hip/hip_runtime.h>

// Problem constants (from reference)
#define NSTARS 2048
#define BATCH  256
#define PF     28
#define NGE    512
#define GF     32
#define OPD2   65536   // 256*256
#define KTOT   (PF + GF)  // 60
#define TM     32      // batches per block in main kernel
// main kernel: 256 threads * float4 = 1024 ij per block

// ---------------------------------------------------------------------------
// Kernel 1: index search + W = [interm_poly | interm_graph] (k-major layout)
// Wt[k*BATCH + b], k in [0,60)
// ---------------------------------------------------------------------------
__global__ __launch_bounds__(256) void prep_kernel(
    const float* __restrict__ positions,  const float* __restrict__ obs_pos,
    const float* __restrict__ poly_dic,   const float* __restrict__ graph_dic,
    const float* __restrict__ alpha_poly, const float* __restrict__ alpha_graph,
    float* __restrict__ Wt)
{
    const int b = blockIdx.x;   // batch row
    const int t = threadIdx.x;  // 256 threads

    const float p0 = positions[2 * b];
    const float p1 = positions[2 * b + 1];

    // Faithful to argmax(eq.reshape(B,-1))//2 : first star n (row-major over
    // (n, coord)) where EITHER coordinate matches; all-false -> 0.
    int cand = 0x7fffffff;
    #pragma unroll
    for (int i = 0; i < NSTARS / 256; ++i) {
        const int n = t + i * 256;
        const float o0 = obs_pos[2 * n];
        const float o1 = obs_pos[2 * n + 1];
        if (o0 == p0 || o1 == p1) cand = min(cand, n);
    }
    __shared__ int smin[256];
    smin[t] = cand;
    __syncthreads();
    for (int s = 128; s > 0; s >>= 1) {
        if (t < s) smin[t] = min(smin[t], smin[t + s]);
        __syncthreads();
    }
    int idx = smin[0];
    if (idx == 0x7fffffff) idx = 0;  // argmax of all-False returns 0

    // interm_poly[j] = sum_p poly_dic[idx,p] * alpha_poly[p,j]
    if (t < PF) {
        float acc = 0.f;
        #pragma unroll
        for (int p = 0; p < PF; ++p)
            acc += poly_dic[idx * PF + p] * alpha_poly[p * PF + t];
        Wt[t * BATCH + b] = acc;
    }

    // interm_graph[g] = sum_e graph_dic[idx,e] * alpha_graph[e,g]
    // 8 partials of 64 elements each, reduced in LDS.
    __shared__ float psum[8][GF];
    {
        const int g = t & 31;
        const int r = t >> 5;
        float acc = 0.f;
        const int e0 = r * (NGE / 8);
        for (int e = e0; e < e0 + NGE / 8; ++e)
            acc += graph_dic[idx * NGE + e] * alpha_graph[e * GF + g];
        psum[r][g] = acc;
    }
    __syncthreads();
    if (t < GF) {
        float acc = 0.f;
        #pragma unroll
        for (int r = 0; r < 8; ++r) acc += psum[r][t];
        Wt[(PF + t) * BATCH + b] = acc;
    }
}

// ---------------------------------------------------------------------------
// Kernel 2: out[b, ij] = sum_k Wt[k, b] * S[k, ij]
// Tile: TM=32 batches x 1024 ij per block (256 thr x float4).
// Wt addresses are block-uniform -> scalar loads; inner loop = pure v_fmac.
// ---------------------------------------------------------------------------
__global__ __launch_bounds__(256) void main_kernel(
    const float* __restrict__ S_poly, const float* __restrict__ S_graph,
    const float* __restrict__ Wt, float* __restrict__ out)
{
    const int t  = threadIdx.x;
    const int ij = blockIdx.x * 1024 + t * 4;
    const int b0 = blockIdx.y * TM;

    float4 acc[TM];
    #pragma unroll
    for (int b = 0; b < TM; ++b) acc[b] = make_float4(0.f, 0.f, 0.f, 0.f);

    const float* __restrict__ wp = Wt + b0;

    #pragma unroll 2
    for (int k = 0; k < PF; ++k) {
        const float4 s = *reinterpret_cast<const float4*>(
            S_poly + (size_t)k * OPD2 + ij);
        #pragma unroll
        for (int b = 0; b < TM; ++b) {
            const float w = wp[k * BATCH + b];
            acc[b].x += w * s.x;
            acc[b].y += w * s.y;
            acc[b].z += w * s.z;
            acc[b].w += w * s.w;
        }
    }
    #pragma unroll 2
    for (int k = 0; k < GF; ++k) {
        const float4 s = *reinterpret_cast<const float4*>(
            S_graph + (size_t)k * OPD2 + ij);
        #pragma unroll
        for (int b = 0; b < TM; ++b) {
            const float w = wp[(PF + k) * BATCH + b];
            acc[b].x += w * s.x;
            acc[b].y += w * s.y;
            acc[b].z += w * s.z;
            acc[b].w += w * s.w;
        }
    }

    #pragma unroll
    for (int b = 0; b < TM; ++b) {
        *reinterpret_cast<float4*>(out + (size_t)(b0 + b) * OPD2 + ij) = acc[b];
    }
}

// ---------------------------------------------------------------------------
extern "C" void kernel_launch(void* const* d_in, const int* in_sizes, int n_in,
                              void* d_out, int out_size, void* d_ws, size_t ws_size,
                              hipStream_t stream) {
    const float* positions   = (const float*)d_in[0];  // (256, 2)
    const float* obs_pos     = (const float*)d_in[1];  // (2048, 2)
    const float* poly_dic    = (const float*)d_in[2];  // (2048, 28)
    const float* graph_dic   = (const float*)d_in[3];  // (2048, 512)
    const float* alpha_poly  = (const float*)d_in[4];  // (28, 28)
    const float* alpha_graph = (const float*)d_in[5];  // (512, 32)
    const float* S_poly      = (const float*)d_in[6];  // (28, 256, 256)
    const float* S_graph     = (const float*)d_in[7];  // (32, 256, 256)
    float* out = (float*)d_out;                        // (256, 256, 256)

    float* Wt = (float*)d_ws;  // KTOT * BATCH floats = 240 KB

    prep_kernel<<<BATCH, 256, 0, stream>>>(positions, obs_pos, poly_dic,
                                           graph_dic, alpha_poly, alpha_graph,
                                           Wt);

    dim3 grid(OPD2 / 1024, BATCH / TM);  // 64 x 8 = 512 blocks
    main_kernel<<<grid, 256, 0, stream>>>(S_poly, S_graph, Wt, out);
}